// Round 3
// baseline (363.341 us; speedup 1.0000x reference)
//
#include <hip/hip_runtime.h>
#include <hip/hip_bf16.h>
#include <math.h>

// Problem constants
#define BB 32
#define CI 64
#define CO 64
#define HH 128
#define WW 128
#define KK 4
#define HID 16

typedef __attribute__((ext_vector_type(8)))  __bf16 bf16x8;
typedef __attribute__((ext_vector_type(16))) float  floatx16;

__device__ __forceinline__ unsigned short f2bf(float f) {
    union { float f; unsigned int u; } a; a.f = f;
    unsigned int u = a.u;
    unsigned int r = (u + 0x7fffu + ((u >> 16) & 1u)) >> 16;  // RNE
    return (unsigned short)r;
}

// xbf layout: [b][g(4 ic-chunks)][y(128)][xi(130, guard cols 0 & 129)][16 ic]
#define XROW 130
#define XPLANE (128 * XROW * 16)   // elements per (b,g) plane

// ---------------------------------------------------------------------------
// Kernel 1: prepass — read x (f32), write bf16 transposed xbf + global pool g.
// One block per (y, b). LDS transpose tile [128 px][72-stride ic].
// ---------------------------------------------------------------------------
__global__ __launch_bounds__(256) void prepass_kernel(
    const float* __restrict__ x, unsigned short* __restrict__ xbf,
    float* __restrict__ g) {
    const int y = blockIdx.x;
    const int b = blockIdx.y;
    const int t = threadIdx.x;
    __shared__ __align__(16) unsigned short tile[128 * 72];

    // read rows (coalesced float4), transpose into LDS, rowsum -> pool
    for (int j = 0; j < 8; j++) {
        int idx = t + j * 256;
        int ic = idx >> 5;
        int xq = idx & 31;
        const float4 v = *reinterpret_cast<const float4*>(
            x + (((size_t)(b * CI + ic)) * HH + y) * WW + xq * 4);
        tile[(xq * 4 + 0) * 72 + ic] = f2bf(v.x);
        tile[(xq * 4 + 1) * 72 + ic] = f2bf(v.y);
        tile[(xq * 4 + 2) * 72 + ic] = f2bf(v.z);
        tile[(xq * 4 + 3) * 72 + ic] = f2bf(v.w);
        float s = v.x + v.y + v.z + v.w;
        for (int off = 16; off > 0; off >>= 1) s += __shfl_down(s, off, 32);
        if ((t & 31) == 0) atomicAdd(&g[b * CI + ic], s * (1.0f / (HH * WW)));
    }
    __syncthreads();

    // write xbf: per (g, x, half) one b128; lanes contiguous
    unsigned short* dst_b = xbf + (size_t)b * 4 * XPLANE + (size_t)y * (XROW * 16);
    for (int j = 0; j < 4; j++) {
        int idx = t + j * 256;          // 0..1023
        int h  = idx & 1;
        int xp = (idx >> 1) & 127;
        int gg = idx >> 8;
        uint4 v = *reinterpret_cast<const uint4*>(&tile[xp * 72 + gg * 16 + h * 8]);
        *reinterpret_cast<uint4*>(dst_b + (size_t)gg * XPLANE + (xp + 1) * 16 + h * 8) = v;
    }
    // guard columns xi=0 and xi=129 -> zeros
    if (t < 16) {
        int h  = t & 1;
        int gg = (t >> 1) & 3;
        int xi = (t >> 3) * 129;
        uint4 z = make_uint4(0, 0, 0, 0);
        *reinterpret_cast<uint4*>(dst_b + (size_t)gg * XPLANE + xi * 16 + h * 8) = z;
    }
}

// ---------------------------------------------------------------------------
// Kernel 2: attention MLP + 5 heads. One wave per batch.
// ---------------------------------------------------------------------------
__global__ __launch_bounds__(64) void attn_kernel(
    const float* __restrict__ g,
    const float* __restrict__ mlp_w, const float* __restrict__ mlp_b,
    const float* __restrict__ wK, const float* __restrict__ bK,
    const float* __restrict__ wO, const float* __restrict__ bO,
    const float* __restrict__ wI, const float* __restrict__ bI,
    const float* __restrict__ wH, const float* __restrict__ bH,
    const float* __restrict__ wW, const float* __restrict__ bW,
    float* __restrict__ aK, float* __restrict__ aO, float* __restrict__ aI,
    float* __restrict__ aH, float* __restrict__ aW) {
    int b = blockIdx.x;
    int t = threadIdx.x;
    __shared__ float sg[CI];
    __shared__ float sh[HID];
    __shared__ float sK[KK];
    __shared__ float sH[3];
    __shared__ float sW[3];

    sg[t] = g[b * CI + t];
    __syncthreads();

    if (t < HID) {
        float s = mlp_b[t];
        for (int c = 0; c < CI; c++) s = fmaf(mlp_w[t * CI + c], sg[c], s);
        sh[t] = fmaxf(s, 0.f);
    }
    __syncthreads();

    {
        float sO = bO[t], sI = bI[t];
        for (int j = 0; j < HID; j++) {
            float hv = sh[j];
            sO = fmaf(wO[t * HID + j], hv, sO);
            sI = fmaf(wI[t * HID + j], hv, sI);
        }
        aO[b * CO + t] = 1.f / (1.f + expf(-sO));
        aI[b * CI + t] = 1.f / (1.f + expf(-sI));
    }
    if (t < KK) {
        float s = bK[t];
        for (int j = 0; j < HID; j++) s = fmaf(wK[t * HID + j], sh[j], s);
        sK[t] = s;
    }
    if (t < 3) {
        float s = bH[t];
        for (int j = 0; j < HID; j++) s = fmaf(wH[t * HID + j], sh[j], s);
        sH[t] = 1.f / (1.f + expf(-s));
        float s2 = bW[t];
        for (int j = 0; j < HID; j++) s2 = fmaf(wW[t * HID + j], sh[j], s2);
        sW[t] = 1.f / (1.f + expf(-s2));
    }
    __syncthreads();

    if (t == 0) {
        float m = fmaxf(fmaxf(sK[0], sK[1]), fmaxf(sK[2], sK[3]));
        float e0 = expf(sK[0] - m), e1 = expf(sK[1] - m);
        float e2 = expf(sK[2] - m), e3 = expf(sK[3] - m);
        float s = e0 + e1 + e2 + e3;
        aK[b * KK + 0] = e0 / s;
        aK[b * KK + 1] = e1 / s;
        aK[b * KK + 2] = e2 / s;
        aK[b * KK + 3] = e3 / s;
        float hs = sH[0] + sH[1] + sH[2] + 1e-6f;
        float wsum = sW[0] + sW[1] + sW[2] + 1e-6f;
        for (int i = 0; i < 3; i++) {
            aH[b * 3 + i] = sH[i] / hs;
            aW[b * 3 + i] = sW[i] / wsum;
        }
    }
}

// ---------------------------------------------------------------------------
// Kernel 3: dynamic weights -> bf16, layout wdbf[b][g][tap][oc][16ic].
// Block: one oc x 8 batches. Weight slice read coalesced ONCE into LDS.
// ---------------------------------------------------------------------------
__global__ __launch_bounds__(256) void wdyn_kernel(
    const float* __restrict__ weight,
    const float* __restrict__ aK, const float* __restrict__ aO,
    const float* __restrict__ aI, const float* __restrict__ aH,
    const float* __restrict__ aW, unsigned short* __restrict__ wdbf) {
    const int o  = blockIdx.x;
    const int bg = blockIdx.y;
    const int t  = threadIdx.x;
    __shared__ float sw4[4 * 576];
    __shared__ float sI[8][64];
    __shared__ float sK4[8][4];
    __shared__ float sO[8];
    __shared__ float sH3[8][3];
    __shared__ float sW3[8][3];

    for (int idx = t; idx < 4 * 576; idx += 256) {
        int k = idx / 576, r = idx % 576;
        sw4[idx] = weight[((size_t)(k * CO + o)) * 576 + r];
    }
    for (int idx = t; idx < 8 * 64; idx += 256) {
        int bl = idx >> 6, i = idx & 63;
        sI[bl][i] = aI[(bg * 8 + bl) * CI + i];
    }
    if (t < 8)  sO[t] = aO[(bg * 8 + t) * CO + o];
    if (t < 32) sK4[t >> 2][t & 3] = aK[(bg * 8 + (t >> 2)) * KK + (t & 3)];
    if (t >= 64 && t < 88)  sH3[(t - 64) / 3][(t - 64) % 3] = aH[(bg * 8 + (t - 64) / 3) * 3 + (t - 64) % 3];
    if (t >= 96 && t < 120) sW3[(t - 96) / 3][(t - 96) % 3] = aW[(bg * 8 + (t - 96) / 3) * 3 + (t - 96) % 3];
    __syncthreads();

    for (int bl = 0; bl < 8; bl++) {
        const int b = bg * 8 + bl;
        for (int idx = t; idx < 576; idx += 256) {
            int icw = idx & 15;
            int tq  = idx >> 4;          // 0..35
            int tap = tq % 9;
            int gg  = tq / 9;
            int i   = gg * 16 + icw;
            float s = sK4[bl][0] * sw4[0 * 576 + i * 9 + tap]
                    + sK4[bl][1] * sw4[1 * 576 + i * 9 + tap]
                    + sK4[bl][2] * sw4[2 * 576 + i * 9 + tap]
                    + sK4[bl][3] * sw4[3 * 576 + i * 9 + tap];
            float v = s * sO[bl] * sI[bl][i] * sH3[bl][tap / 3] * sW3[bl][tap % 3];
            wdbf[((((size_t)b * 4 + gg) * 9 + tap) * CO + o) * 16 + icw] = f2bf(v);
        }
    }
}

// ---------------------------------------------------------------------------
// Kernel 4: implicit-GEMM conv. Grid (16 yblocks, 32 b), 512 thr = 8 waves.
// Wave = 1 output row x 128 px x 64 oc; acc = 2(oc) x 4(px) MFMA 32x32 tiles.
// A (weights) from LDS (18.4KB contiguous stage per 16-ic chunk);
// B (x) direct from global xbf — perfectly coalesced 1KB b128 wave-loads.
// ---------------------------------------------------------------------------
__global__ __launch_bounds__(512, 2) void conv_kernel(
    const unsigned short* __restrict__ xbf,
    const unsigned short* __restrict__ wdbf,
    const float* __restrict__ bias, float* __restrict__ out) {
    const int y0 = blockIdx.x * 8;
    const int b  = blockIdx.y;
    const int t  = threadIdx.x;
    const int lane = t & 63;
    const int w    = t >> 6;       // 0..7 -> output row y0+w
    const int l31  = lane & 31;
    const int koct = lane >> 5;

    __shared__ __align__(16) unsigned short sw[9 * 64 * 24];  // 27.6 KB

    floatx16 acc[2][4];
#pragma unroll
    for (int i = 0; i < 2; i++)
#pragma unroll
        for (int j = 0; j < 4; j++)
#pragma unroll
            for (int q = 0; q < 16; q++) acc[i][j][q] = 0.f;

    const unsigned short* xb_b = xbf + (size_t)b * 4 * XPLANE;

    for (int g = 0; g < 4; g++) {
        __syncthreads();
        const unsigned short* wdp = wdbf + (((size_t)b * 4 + g) * 9 * CO * 16);
        for (int idx = t; idx < 1152; idx += 512) {
            int h   = idx & 1;
            int oc  = (idx >> 1) & 63;
            int tap = idx >> 7;
            uint4 v = *reinterpret_cast<const uint4*>(wdp + idx * 8);
            *reinterpret_cast<uint4*>(&sw[(tap * 64 + oc) * 24 + h * 8]) = v;
        }
        __syncthreads();

        const unsigned short* gplane = xb_b + (size_t)g * XPLANE;
#pragma unroll
        for (int kh = 0; kh < 3; kh++) {
            const int row = y0 + w + kh - 1;
            if ((unsigned)row < (unsigned)HH) {
                const unsigned short* rp =
                    gplane + ((size_t)row * XROW + l31) * 16 + koct * 8;
#pragma unroll
                for (int kw = 0; kw < 3; kw++) {
                    const int tap = kh * 3 + kw;
                    bf16x8 a0 = *reinterpret_cast<const bf16x8*>(&sw[(tap * 64 + l31) * 24 + koct * 8]);
                    bf16x8 a1 = *reinterpret_cast<const bf16x8*>(&sw[(tap * 64 + 32 + l31) * 24 + koct * 8]);
#pragma unroll
                    for (int pt = 0; pt < 4; pt++) {
                        bf16x8 bf = *reinterpret_cast<const bf16x8*>(rp + (pt * 32 + kw) * 16);
                        acc[0][pt] = __builtin_amdgcn_mfma_f32_32x32x16_bf16(a0, bf, acc[0][pt], 0, 0, 0);
                        acc[1][pt] = __builtin_amdgcn_mfma_f32_32x32x16_bf16(a1, bf, acc[1][pt], 0, 0, 0);
                    }
                }
            }
        }
    }

    // epilogue: C/D map col(px)=lane&31, row(oc)=(r&3)+8*(r>>2)+4*koct
    const int y = y0 + w;
    float* ob = out + (size_t)b * CO * HH * WW + (size_t)y * WW;
#pragma unroll
    for (int mt = 0; mt < 2; mt++) {
#pragma unroll
        for (int r = 0; r < 16; r++) {
            const int oc = mt * 32 + (r & 3) + 8 * (r >> 2) + 4 * koct;
            const float bv = bias[oc];
#pragma unroll
            for (int pt = 0; pt < 4; pt++) {
                ob[(size_t)oc * (HH * WW) + pt * 32 + l31] = acc[mt][pt][r] + bv;
            }
        }
    }
}

// ---------------------------------------------------------------------------
extern "C" void kernel_launch(void* const* d_in, const int* in_sizes, int n_in,
                              void* d_out, int out_size, void* d_ws, size_t ws_size,
                              hipStream_t stream) {
    const float* x     = (const float*)d_in[0];
    const float* weight= (const float*)d_in[1];
    const float* bias  = (const float*)d_in[2];
    const float* mlp_w = (const float*)d_in[3];
    const float* mlp_b = (const float*)d_in[4];
    const float* wK    = (const float*)d_in[5];
    const float* bK    = (const float*)d_in[6];
    const float* wO    = (const float*)d_in[7];
    const float* bO    = (const float*)d_in[8];
    const float* wI    = (const float*)d_in[9];
    const float* bI    = (const float*)d_in[10];
    const float* wH    = (const float*)d_in[11];
    const float* bH    = (const float*)d_in[12];
    const float* wW    = (const float*)d_in[13];
    const float* bW    = (const float*)d_in[14];
    float* out = (float*)d_out;

    // workspace layout
    float* ws = (float*)d_ws;
    float* g  = ws;            // 2048
    float* aK = g + 2048;      // 128
    float* aO = aK + 128;      // 2048
    float* aI = aO + 2048;     // 2048
    float* aH = aI + 2048;     // 96
    float* aW = aH + 96;       // 96
    unsigned short* wdbf = (unsigned short*)(ws + 8192);          // 2.36 MB
    unsigned short* xbf  = wdbf + (size_t)BB * 4 * 9 * CO * 16;   // 68.2 MB

    hipMemsetAsync(g, 0, 2048 * sizeof(float), stream);  // pool accumulators
    prepass_kernel<<<dim3(HH, BB), 256, 0, stream>>>(x, xbf, g);
    attn_kernel<<<BB, 64, 0, stream>>>(g, mlp_w, mlp_b, wK, bK, wO, bO, wI, bI,
                                       wH, bH, wW, bW, aK, aO, aI, aH, aW);
    wdyn_kernel<<<dim3(CO, 4), 256, 0, stream>>>(weight, aK, aO, aI, aH, aW, wdbf);
    conv_kernel<<<dim3(HH / 8, BB), 512, 0, stream>>>(xbf, wdbf, bias, out);
}